// Round 1
// baseline (723.095 us; speedup 1.0000x reference)
//
#include <hip/hip_runtime.h>
#include <hip/hip_bf16.h>

#define HIDDEN 1024
#define INTER 4096
#define NEXP 8
#define T_TOK 2048

typedef short bf16x8 __attribute__((ext_vector_type(8)));
typedef float f32x4 __attribute__((ext_vector_type(4)));

__device__ __forceinline__ unsigned short f2bf(float f) {
    union { float f; unsigned int u; } v; v.f = f;
    unsigned int u = v.u;
    unsigned int r = (u + 0x7FFFu + ((u >> 16) & 1u)) >> 16;
    return (unsigned short)r;
}

// XOR swizzle for 128-byte-stride LDS rows (64 bf16/row): spreads the
// 16-lane same-column read across 8 bank groups (G4 fix).
__device__ __forceinline__ unsigned int swz(unsigned int row, unsigned int colByte) {
    return (row * 128u + colByte) ^ ((row & 7u) << 4);
}

// ---------------- K1: router (fp32 exact) ----------------
__global__ void router_kernel(const float* __restrict__ x,
                              const float* __restrict__ rw,
                              float* __restrict__ logits_out,
                              int* __restrict__ counts,
                              int* __restrict__ ids,
                              float* __restrict__ wts) {
    int t = blockIdx.x * 4 + (threadIdx.x >> 6);
    int lane = threadIdx.x & 63;
    if (t >= T_TOK) return;
    const float4* xr = (const float4*)(x + (size_t)t * HIDDEN);
    float acc[NEXP];
#pragma unroll
    for (int e = 0; e < NEXP; e++) acc[e] = 0.f;
#pragma unroll
    for (int c = 0; c < 4; c++) {
        float4 xv = xr[lane + c * 64];
#pragma unroll
        for (int e = 0; e < NEXP; e++) {
            float4 wv = ((const float4*)(rw + (size_t)e * HIDDEN))[lane + c * 64];
            acc[e] += xv.x * wv.x + xv.y * wv.y + xv.z * wv.z + xv.w * wv.w;
        }
    }
#pragma unroll
    for (int e = 0; e < NEXP; e++) {
        float v = acc[e];
        for (int off = 32; off >= 1; off >>= 1) v += __shfl_xor(v, off, 64);
        acc[e] = v;
    }
    if (lane == 0) {
        float* lo = logits_out + (size_t)t * NEXP;
        float mx = acc[0];
#pragma unroll
        for (int e = 1; e < NEXP; e++) mx = fmaxf(mx, acc[e]);
        float p[NEXP], s = 0.f;
#pragma unroll
        for (int e = 0; e < NEXP; e++) { p[e] = __expf(acc[e] - mx); s += p[e]; }
        float inv = 1.f / s;
#pragma unroll
        for (int e = 0; e < NEXP; e++) { p[e] *= inv; lo[e] = acc[e]; }
        int i1 = 0;
#pragma unroll
        for (int e = 1; e < NEXP; e++) if (p[e] > p[i1]) i1 = e;
        int i2 = (i1 == 0) ? 1 : 0;
#pragma unroll
        for (int e = 0; e < NEXP; e++) if (e != i1 && p[e] > p[i2]) { if (e < i2 || p[e] > p[i2]) i2 = e; }
        // strict > keeps lowest index on ties (matches jax top_k)
        int s1 = atomicAdd(&counts[i1], 1);
        ids[i1 * T_TOK + s1] = t; wts[i1 * T_TOK + s1] = p[i1];
        int s2 = atomicAdd(&counts[i2], 1);
        ids[i2 * T_TOK + s2] = t; wts[i2 * T_TOK + s2] = p[i2];
    }
}

// ---------------- K1b: exclusive scan of counts ----------------
__global__ void scan_kernel(const int* __restrict__ counts, int* __restrict__ offsets) {
    if (threadIdx.x == 0) {
        int s = 0;
        for (int e = 0; e < NEXP; e++) { offsets[e] = s; s += counts[e]; }
    }
}

// ---------------- K2: fused gate+up grouped GEMM + SwiGLU ----------------
// tile: 128 tokens x 64 inter, BK=64, 4 waves (2x2), 16x16x32 bf16 MFMA
__global__ __launch_bounds__(256, 2) void gemm_gu(
    const float* __restrict__ x, const float* __restrict__ gw, const float* __restrict__ uw,
    const int* __restrict__ counts, const int* __restrict__ offsets,
    const int* __restrict__ ids, unsigned short* __restrict__ h) {
    const int e = blockIdx.z;
    const int cnt = counts[e];
    const int mt = blockIdx.y;
    if (mt * 128 >= cnt) return;
    const int nt = blockIdx.x;
    const int tid = threadIdx.x;
    const int lane = tid & 63, wid = tid >> 6;
    const int wm = wid >> 1, wn = wid & 1;

    __shared__ __align__(16) unsigned short sA[128 * 64];
    __shared__ __align__(16) unsigned short sBg[64 * 64];
    __shared__ __align__(16) unsigned short sBu[64 * 64];

    const float* aptr[8];
    unsigned int wAoff[8];
#pragma unroll
    for (int i = 0; i < 8; i++) {
        int idx = i * 256 + tid;
        int row = idx >> 4, c4 = idx & 15;
        int li = mt * 128 + row; if (li >= cnt) li = cnt - 1;
        int gid = ids[e * T_TOK + li];
        aptr[i] = x + (size_t)gid * HIDDEN + c4 * 4;
        wAoff[i] = swz(row, c4 * 8);
    }
    const float *gptr[4], *uptr[4];
    unsigned int wBoff[4];
#pragma unroll
    for (int j = 0; j < 4; j++) {
        int idx = j * 256 + tid;
        int row = idx >> 4, c4 = idx & 15;
        size_t base = (size_t)e * INTER * HIDDEN + (size_t)(nt * 64 + row) * HIDDEN + c4 * 4;
        gptr[j] = gw + base;
        uptr[j] = uw + base;
        wBoff[j] = swz(row, c4 * 8);
    }

    f32x4 accg[4][2], accu[4][2];
#pragma unroll
    for (int mf = 0; mf < 4; mf++)
#pragma unroll
        for (int nf = 0; nf < 2; nf++)
#pragma unroll
            for (int v = 0; v < 4; v++) { accg[mf][nf][v] = 0.f; accu[mf][nf][v] = 0.f; }

    for (int kt = 0; kt < HIDDEN / 64; kt++) {
        float4 av[8], gv[4], uv[4];
#pragma unroll
        for (int i = 0; i < 8; i++) av[i] = *(const float4*)(aptr[i] + kt * 64);
#pragma unroll
        for (int j = 0; j < 4; j++) {
            gv[j] = *(const float4*)(gptr[j] + kt * 64);
            uv[j] = *(const float4*)(uptr[j] + kt * 64);
        }
        __syncthreads();
#pragma unroll
        for (int i = 0; i < 8; i++) {
            uint2 w;
            w.x = (unsigned int)f2bf(av[i].x) | ((unsigned int)f2bf(av[i].y) << 16);
            w.y = (unsigned int)f2bf(av[i].z) | ((unsigned int)f2bf(av[i].w) << 16);
            *(uint2*)((char*)sA + wAoff[i]) = w;
        }
#pragma unroll
        for (int j = 0; j < 4; j++) {
            uint2 w;
            w.x = (unsigned int)f2bf(gv[j].x) | ((unsigned int)f2bf(gv[j].y) << 16);
            w.y = (unsigned int)f2bf(gv[j].z) | ((unsigned int)f2bf(gv[j].w) << 16);
            *(uint2*)((char*)sBg + wBoff[j]) = w;
            w.x = (unsigned int)f2bf(uv[j].x) | ((unsigned int)f2bf(uv[j].y) << 16);
            w.y = (unsigned int)f2bf(uv[j].z) | ((unsigned int)f2bf(uv[j].w) << 16);
            *(uint2*)((char*)sBu + wBoff[j]) = w;
        }
        __syncthreads();
#pragma unroll
        for (int ks = 0; ks < 2; ks++) {
            int kb = ks * 64 + ((lane >> 4) << 4);
            bf16x8 af[4], bg[2], bu[2];
#pragma unroll
            for (int mf = 0; mf < 4; mf++) {
                int row = wm * 64 + mf * 16 + (lane & 15);
                af[mf] = *(const bf16x8*)((const char*)sA + swz(row, kb));
            }
#pragma unroll
            for (int nf = 0; nf < 2; nf++) {
                int row = wn * 32 + nf * 16 + (lane & 15);
                bg[nf] = *(const bf16x8*)((const char*)sBg + swz(row, kb));
                bu[nf] = *(const bf16x8*)((const char*)sBu + swz(row, kb));
            }
#pragma unroll
            for (int mf = 0; mf < 4; mf++)
#pragma unroll
                for (int nf = 0; nf < 2; nf++) {
                    accg[mf][nf] = __builtin_amdgcn_mfma_f32_16x16x32_bf16(af[mf], bg[nf], accg[mf][nf], 0, 0, 0);
                    accu[mf][nf] = __builtin_amdgcn_mfma_f32_16x16x32_bf16(af[mf], bu[nf], accu[mf][nf], 0, 0, 0);
                }
        }
    }
    const int hoff = offsets[e];
#pragma unroll
    for (int mf = 0; mf < 4; mf++)
#pragma unroll
        for (int v = 0; v < 4; v++) {
            int il = wm * 64 + mf * 16 + ((lane >> 4) << 2) + v;
            int i = mt * 128 + il;
            if (i < cnt) {
                size_t rowbase = (size_t)(hoff + i) * INTER + nt * 64 + wn * 32 + (lane & 15);
#pragma unroll
                for (int nf = 0; nf < 2; nf++) {
                    float g = accg[mf][nf][v], u = accu[mf][nf][v];
                    float sg = g / (1.f + __expf(-g));
                    h[rowbase + nf * 16] = f2bf(sg * u);
                }
            }
        }
}

// ---------------- K3: down grouped GEMM + weighted scatter-add ----------------
// tile: 128 rows x 64 hidden, BK=64
__global__ __launch_bounds__(256, 2) void gemm_down(
    const unsigned short* __restrict__ h, const float* __restrict__ dw,
    const int* __restrict__ counts, const int* __restrict__ offsets,
    const int* __restrict__ ids, const float* __restrict__ wts,
    float* __restrict__ out) {
    const int e = blockIdx.z;
    const int cnt = counts[e];
    const int mt = blockIdx.y;
    if (mt * 128 >= cnt) return;
    const int nt = blockIdx.x;
    const int tid = threadIdx.x;
    const int lane = tid & 63, wid = tid >> 6;
    const int wm = wid >> 1, wn = wid & 1;

    __shared__ __align__(16) unsigned short sA[128 * 64];
    __shared__ __align__(16) unsigned short sB[64 * 64];

    const int hoff = offsets[e];
    const unsigned short* aptr[4];
    unsigned int wAoff[4];
#pragma unroll
    for (int j = 0; j < 4; j++) {
        int idx = j * 256 + tid;
        int row = idx >> 3, c8 = idx & 7;
        int li = mt * 128 + row; if (li >= cnt) li = cnt - 1;
        int hrow = hoff + li; if (hrow > 4095) hrow = 4095;
        aptr[j] = h + (size_t)hrow * INTER + c8 * 8;
        wAoff[j] = swz(row, c8 * 16);
    }
    const float* bptr[4];
    unsigned int wBoff[4];
#pragma unroll
    for (int j = 0; j < 4; j++) {
        int idx = j * 256 + tid;
        int row = idx >> 4, c4 = idx & 15;
        bptr[j] = dw + (size_t)e * HIDDEN * INTER + (size_t)(nt * 64 + row) * INTER + c4 * 4;
        wBoff[j] = swz(row, c4 * 8);
    }

    f32x4 acc[4][2];
#pragma unroll
    for (int mf = 0; mf < 4; mf++)
#pragma unroll
        for (int nf = 0; nf < 2; nf++)
#pragma unroll
            for (int v = 0; v < 4; v++) acc[mf][nf][v] = 0.f;

    for (int kt = 0; kt < INTER / 64; kt++) {
        int4 avv[4]; float4 bv[4];
#pragma unroll
        for (int j = 0; j < 4; j++) {
            avv[j] = *(const int4*)(aptr[j] + kt * 64);
            bv[j] = *(const float4*)(bptr[j] + kt * 64);
        }
        __syncthreads();
#pragma unroll
        for (int j = 0; j < 4; j++) {
            *(int4*)((char*)sA + wAoff[j]) = avv[j];
            uint2 w;
            w.x = (unsigned int)f2bf(bv[j].x) | ((unsigned int)f2bf(bv[j].y) << 16);
            w.y = (unsigned int)f2bf(bv[j].z) | ((unsigned int)f2bf(bv[j].w) << 16);
            *(uint2*)((char*)sB + wBoff[j]) = w;
        }
        __syncthreads();
#pragma unroll
        for (int ks = 0; ks < 2; ks++) {
            int kb = ks * 64 + ((lane >> 4) << 4);
            bf16x8 af[4], bf[2];
#pragma unroll
            for (int mf = 0; mf < 4; mf++) {
                int row = wm * 64 + mf * 16 + (lane & 15);
                af[mf] = *(const bf16x8*)((const char*)sA + swz(row, kb));
            }
#pragma unroll
            for (int nf = 0; nf < 2; nf++) {
                int row = wn * 32 + nf * 16 + (lane & 15);
                bf[nf] = *(const bf16x8*)((const char*)sB + swz(row, kb));
            }
#pragma unroll
            for (int mf = 0; mf < 4; mf++)
#pragma unroll
                for (int nf = 0; nf < 2; nf++)
                    acc[mf][nf] = __builtin_amdgcn_mfma_f32_16x16x32_bf16(af[mf], bf[nf], acc[mf][nf], 0, 0, 0);
        }
    }
#pragma unroll
    for (int mf = 0; mf < 4; mf++)
#pragma unroll
        for (int v = 0; v < 4; v++) {
            int il = wm * 64 + mf * 16 + ((lane >> 4) << 2) + v;
            int i = mt * 128 + il;
            if (i < cnt) {
                int t = ids[e * T_TOK + i];
                float w = wts[e * T_TOK + i];
                float* orow = out + (size_t)t * HIDDEN + nt * 64 + wn * 32 + (lane & 15);
#pragma unroll
                for (int nf = 0; nf < 2; nf++)
                    atomicAdd(orow + nf * 16, w * acc[mf][nf][v]);
            }
        }
}

extern "C" void kernel_launch(void* const* d_in, const int* in_sizes, int n_in,
                              void* d_out, int out_size, void* d_ws, size_t ws_size,
                              hipStream_t stream) {
    const float* x  = (const float*)d_in[0];
    const float* rw = (const float*)d_in[1];
    const float* gw = (const float*)d_in[2];
    const float* uw = (const float*)d_in[3];
    const float* dw = (const float*)d_in[4];
    float* out = (float*)d_out;
    float* logits = out + (size_t)T_TOK * HIDDEN;

    int* counts  = (int*)d_ws;
    int* offsets = counts + 8;
    int* ids     = (int*)((char*)d_ws + 64);
    float* wts   = (float*)((char*)d_ws + 64 + 8 * T_TOK * 4);
    unsigned short* h = (unsigned short*)((char*)d_ws + 262144);

    hipMemsetAsync(out, 0, (size_t)T_TOK * HIDDEN * sizeof(float), stream);
    hipMemsetAsync(counts, 0, 8 * sizeof(int), stream);

    router_kernel<<<T_TOK / 4, 256, 0, stream>>>(x, rw, logits, counts, ids, wts);
    scan_kernel<<<1, 64, 0, stream>>>(counts, offsets);
    gemm_gu<<<dim3(INTER / 64, 16, NEXP), 256, 0, stream>>>(x, gw, uw, counts, offsets, ids, h);
    gemm_down<<<dim3(HIDDEN / 64, 16, NEXP), 256, 0, stream>>>(h, dw, counts, offsets, ids, wts, out);
}

// Round 2
// 426.726 us; speedup vs baseline: 1.6945x; 1.6945x over previous
//
#include <hip/hip_runtime.h>
#include <hip/hip_bf16.h>

#define HIDDEN 1024
#define INTER 4096
#define NEXP 8
#define T_TOK 2048

typedef short bf16x8 __attribute__((ext_vector_type(8)));
typedef float f32x4 __attribute__((ext_vector_type(4)));

__device__ __forceinline__ unsigned short f2bf(float f) {
    union { float f; unsigned int u; } v; v.f = f;
    unsigned int u = v.u;
    unsigned int r = (u + 0x7FFFu + ((u >> 16) & 1u)) >> 16;
    return (unsigned short)r;
}

// truncating fp32->bf16 pack of 4 floats -> 2 dwords (v_perm_b32 x2).
// RNE not needed: ~10x absmax margin measured in R1.
__device__ __forceinline__ uint2 pack4trunc(float4 v) {
    union { float4 f; unsigned short s[8]; } u; u.f = v;
    uint2 r;
    r.x = (unsigned int)u.s[1] | ((unsigned int)u.s[3] << 16);
    r.y = (unsigned int)u.s[5] | ((unsigned int)u.s[7] << 16);
    return r;
}

// XOR swizzle for 128-byte-stride LDS rows (64 bf16/row): 16 lanes reading the
// same 16B column of 16 consecutive rows spread across 8 bank groups (G4).
__device__ __forceinline__ unsigned int swz(unsigned int row, unsigned int colByte) {
    return (row * 128u + colByte) ^ ((row & 7u) << 4);
}

// ---------------- K1: router (fp32 exact) ----------------
__global__ void router_kernel(const float* __restrict__ x,
                              const float* __restrict__ rw,
                              float* __restrict__ logits_out,
                              int* __restrict__ counts,
                              int* __restrict__ ids,
                              float* __restrict__ wts) {
    int t = blockIdx.x * 4 + (threadIdx.x >> 6);
    int lane = threadIdx.x & 63;
    if (t >= T_TOK) return;
    const float4* xr = (const float4*)(x + (size_t)t * HIDDEN);
    float acc[NEXP];
#pragma unroll
    for (int e = 0; e < NEXP; e++) acc[e] = 0.f;
#pragma unroll
    for (int c = 0; c < 4; c++) {
        float4 xv = xr[lane + c * 64];
#pragma unroll
        for (int e = 0; e < NEXP; e++) {
            float4 wv = ((const float4*)(rw + (size_t)e * HIDDEN))[lane + c * 64];
            acc[e] += xv.x * wv.x + xv.y * wv.y + xv.z * wv.z + xv.w * wv.w;
        }
    }
#pragma unroll
    for (int e = 0; e < NEXP; e++) {
        float v = acc[e];
        for (int off = 32; off >= 1; off >>= 1) v += __shfl_xor(v, off, 64);
        acc[e] = v;
    }
    if (lane == 0) {
        float* lo = logits_out + (size_t)t * NEXP;
        float mx = acc[0];
#pragma unroll
        for (int e = 1; e < NEXP; e++) mx = fmaxf(mx, acc[e]);
        float p[NEXP], s = 0.f;
#pragma unroll
        for (int e = 0; e < NEXP; e++) { p[e] = __expf(acc[e] - mx); s += p[e]; }
        float inv = 1.f / s;
#pragma unroll
        for (int e = 0; e < NEXP; e++) { p[e] *= inv; lo[e] = acc[e]; }
        int i1 = 0;
#pragma unroll
        for (int e = 1; e < NEXP; e++) if (p[e] > p[i1]) i1 = e;
        int i2 = (i1 == 0) ? 1 : 0;
#pragma unroll
        for (int e = 0; e < NEXP; e++) if (e != i1 && e != i2 && p[e] > p[i2]) i2 = e;
        // strict > keeps lowest index on ties (matches jax top_k)
        int s1 = atomicAdd(&counts[i1], 1);
        ids[i1 * T_TOK + s1] = t; wts[i1 * T_TOK + s1] = p[i1];
        int s2 = atomicAdd(&counts[i2], 1);
        ids[i2 * T_TOK + s2] = t; wts[i2 * T_TOK + s2] = p[i2];
    }
}

// ---------------- K1b: exclusive scan of counts ----------------
__global__ void scan_kernel(const int* __restrict__ counts, int* __restrict__ offsets) {
    if (threadIdx.x == 0) {
        int s = 0;
        for (int e = 0; e < NEXP; e++) { offsets[e] = s; s += counts[e]; }
    }
}

// ---------------- K2: fused gate+up grouped GEMM + SwiGLU ----------------
// tile: 128 tokens x 128 inter, BK=64, 8 waves (2x4), 16x16x32 bf16 MFMA.
// Software pipeline: next tile's global loads issue BEFORE the MFMA phase
// (reg-staged async split, T14) so HBM latency hides under compute.
__global__ __launch_bounds__(512, 2) void gemm_gu(
    const float* __restrict__ x, const float* __restrict__ gw, const float* __restrict__ uw,
    const int* __restrict__ counts, const int* __restrict__ offsets,
    const int* __restrict__ ids, unsigned short* __restrict__ h) {
    const int e = blockIdx.z;
    const int cnt = counts[e];
    const int mt = blockIdx.y;
    if (mt * 128 >= cnt) return;
    const int nt = blockIdx.x;                  // 32 tiles of 128 inter
    const int tid = threadIdx.x;
    const int lane = tid & 63, wid = tid >> 6;
    const int wm = wid >> 2, wn = wid & 3;      // 2 x 4 wave grid

    __shared__ __align__(16) unsigned short sA[128 * 64];
    __shared__ __align__(16) unsigned short sBg[128 * 64];
    __shared__ __align__(16) unsigned short sBu[128 * 64];

    size_t aoff[4], boff[4];
    unsigned int wOff[4];
#pragma unroll
    for (int j = 0; j < 4; j++) {
        int idx = j * 512 + tid;                // 0..2047
        int row = idx >> 4, c4 = idx & 15;
        int li = mt * 128 + row; if (li >= cnt) li = cnt - 1;
        int gid = ids[e * T_TOK + li];
        aoff[j] = (size_t)gid * HIDDEN + c4 * 4;
        boff[j] = (size_t)e * INTER * HIDDEN + (size_t)(nt * 128 + row) * HIDDEN + c4 * 4;
        wOff[j] = swz(row, c4 * 8);
    }

    f32x4 accg[4][2], accu[4][2];
#pragma unroll
    for (int mf = 0; mf < 4; mf++)
#pragma unroll
        for (int nf = 0; nf < 2; nf++)
#pragma unroll
            for (int v = 0; v < 4; v++) { accg[mf][nf][v] = 0.f; accu[mf][nf][v] = 0.f; }

    float4 av[4], gv[4], uv[4];
#pragma unroll
    for (int j = 0; j < 4; j++) {
        av[j] = *(const float4*)(x + aoff[j]);
        gv[j] = *(const float4*)(gw + boff[j]);
        uv[j] = *(const float4*)(uw + boff[j]);
    }

    for (int kt = 0; kt < HIDDEN / 64; kt++) {
        __syncthreads();                        // prev compute done reading LDS
#pragma unroll
        for (int j = 0; j < 4; j++) {
            *(uint2*)((char*)sA  + wOff[j]) = pack4trunc(av[j]);
            *(uint2*)((char*)sBg + wOff[j]) = pack4trunc(gv[j]);
            *(uint2*)((char*)sBu + wOff[j]) = pack4trunc(uv[j]);
        }
        __syncthreads();
        if (kt + 1 < HIDDEN / 64) {             // prefetch next tile (overlaps MFMA)
#pragma unroll
            for (int j = 0; j < 4; j++) {
                av[j] = *(const float4*)(x  + aoff[j] + (kt + 1) * 64);
                gv[j] = *(const float4*)(gw + boff[j] + (kt + 1) * 64);
                uv[j] = *(const float4*)(uw + boff[j] + (kt + 1) * 64);
            }
        }
#pragma unroll
        for (int ks = 0; ks < 2; ks++) {
            int kb = ks * 64 + ((lane >> 4) << 4);
            bf16x8 af[4], bg[2], bu[2];
#pragma unroll
            for (int mf = 0; mf < 4; mf++) {
                int row = wm * 64 + mf * 16 + (lane & 15);
                af[mf] = *(const bf16x8*)((const char*)sA + swz(row, kb));
            }
#pragma unroll
            for (int nf = 0; nf < 2; nf++) {
                int row = wn * 32 + nf * 16 + (lane & 15);
                bg[nf] = *(const bf16x8*)((const char*)sBg + swz(row, kb));
                bu[nf] = *(const bf16x8*)((const char*)sBu + swz(row, kb));
            }
#pragma unroll
            for (int mf = 0; mf < 4; mf++)
#pragma unroll
                for (int nf = 0; nf < 2; nf++) {
                    accg[mf][nf] = __builtin_amdgcn_mfma_f32_16x16x32_bf16(af[mf], bg[nf], accg[mf][nf], 0, 0, 0);
                    accu[mf][nf] = __builtin_amdgcn_mfma_f32_16x16x32_bf16(af[mf], bu[nf], accu[mf][nf], 0, 0, 0);
                }
        }
    }
    const int hoff = offsets[e];
#pragma unroll
    for (int mf = 0; mf < 4; mf++)
#pragma unroll
        for (int v = 0; v < 4; v++) {
            int il = wm * 64 + mf * 16 + ((lane >> 4) << 2) + v;
            int i = mt * 128 + il;
            if (i < cnt) {
                size_t rowbase = (size_t)(hoff + i) * INTER + nt * 128 + wn * 32 + (lane & 15);
#pragma unroll
                for (int nf = 0; nf < 2; nf++) {
                    float g = accg[mf][nf][v], u = accu[mf][nf][v];
                    float sg = g / (1.f + __expf(-g));
                    h[rowbase + nf * 16] = f2bf(sg * u);
                }
            }
        }
}

// ---------------- K3: down grouped GEMM + weighted scatter-add ----------------
// tile: 128 rows x 128 hidden, BK=64, 8 waves, K split 4 ways (atomic combine)
__global__ __launch_bounds__(512, 2) void gemm_down(
    const unsigned short* __restrict__ h, const float* __restrict__ dw,
    const int* __restrict__ counts, const int* __restrict__ offsets,
    const int* __restrict__ ids, const float* __restrict__ wts,
    float* __restrict__ out) {
    const int ez = blockIdx.z;                  // e*4 + ksplit
    const int e = ez >> 2, ksp = ez & 3;
    const int cnt = counts[e];
    const int mt = blockIdx.y;
    if (mt * 128 >= cnt) return;
    const int nt = blockIdx.x;                  // 8 tiles of 128 hidden
    const int tid = threadIdx.x;
    const int lane = tid & 63, wid = tid >> 6;
    const int wm = wid >> 2, wn = wid & 3;

    __shared__ __align__(16) unsigned short sA[128 * 64];
    __shared__ __align__(16) unsigned short sB[128 * 64];

    const int hoff = offsets[e];
    size_t aoff[2], boff[4];
    unsigned int wAoff[2], wBoff[4];
#pragma unroll
    for (int j = 0; j < 2; j++) {
        int idx = j * 512 + tid;                // 0..1023
        int row = idx >> 3, c8 = idx & 7;
        int li = mt * 128 + row; if (li >= cnt) li = cnt - 1;
        aoff[j] = (size_t)(hoff + li) * INTER + ksp * 1024 + c8 * 8;
        wAoff[j] = swz(row, c8 * 16);
    }
#pragma unroll
    for (int j = 0; j < 4; j++) {
        int idx = j * 512 + tid;                // 0..2047
        int row = idx >> 4, c4 = idx & 15;
        boff[j] = (size_t)e * HIDDEN * INTER + (size_t)(nt * 128 + row) * INTER + ksp * 1024 + c4 * 4;
        wBoff[j] = swz(row, c4 * 8);
    }

    f32x4 acc[4][2];
#pragma unroll
    for (int mf = 0; mf < 4; mf++)
#pragma unroll
        for (int nf = 0; nf < 2; nf++)
#pragma unroll
            for (int v = 0; v < 4; v++) acc[mf][nf][v] = 0.f;

    int4 avv[2]; float4 bv[4];
#pragma unroll
    for (int j = 0; j < 2; j++) avv[j] = *(const int4*)(h + aoff[j]);
#pragma unroll
    for (int j = 0; j < 4; j++) bv[j] = *(const float4*)(dw + boff[j]);

    for (int kt = 0; kt < 16; kt++) {
        __syncthreads();
#pragma unroll
        for (int j = 0; j < 2; j++) *(int4*)((char*)sA + wAoff[j]) = avv[j];
#pragma unroll
        for (int j = 0; j < 4; j++) *(uint2*)((char*)sB + wBoff[j]) = pack4trunc(bv[j]);
        __syncthreads();
        if (kt + 1 < 16) {
#pragma unroll
            for (int j = 0; j < 2; j++) avv[j] = *(const int4*)(h + aoff[j] + (kt + 1) * 64);
#pragma unroll
            for (int j = 0; j < 4; j++) bv[j] = *(const float4*)(dw + boff[j] + (kt + 1) * 64);
        }
#pragma unroll
        for (int ks = 0; ks < 2; ks++) {
            int kb = ks * 64 + ((lane >> 4) << 4);
            bf16x8 af[4], bf[2];
#pragma unroll
            for (int mf = 0; mf < 4; mf++) {
                int row = wm * 64 + mf * 16 + (lane & 15);
                af[mf] = *(const bf16x8*)((const char*)sA + swz(row, kb));
            }
#pragma unroll
            for (int nf = 0; nf < 2; nf++) {
                int row = wn * 32 + nf * 16 + (lane & 15);
                bf[nf] = *(const bf16x8*)((const char*)sB + swz(row, kb));
            }
#pragma unroll
            for (int mf = 0; mf < 4; mf++)
#pragma unroll
                for (int nf = 0; nf < 2; nf++)
                    acc[mf][nf] = __builtin_amdgcn_mfma_f32_16x16x32_bf16(af[mf], bf[nf], acc[mf][nf], 0, 0, 0);
        }
    }
#pragma unroll
    for (int mf = 0; mf < 4; mf++)
#pragma unroll
        for (int v = 0; v < 4; v++) {
            int il = wm * 64 + mf * 16 + ((lane >> 4) << 2) + v;
            int i = mt * 128 + il;
            if (i < cnt) {
                int t = ids[e * T_TOK + i];
                float w = wts[e * T_TOK + i];
                float* orow = out + (size_t)t * HIDDEN + nt * 128 + wn * 32 + (lane & 15);
#pragma unroll
                for (int nf = 0; nf < 2; nf++)
                    atomicAdd(orow + nf * 16, w * acc[mf][nf][v]);
            }
        }
}

extern "C" void kernel_launch(void* const* d_in, const int* in_sizes, int n_in,
                              void* d_out, int out_size, void* d_ws, size_t ws_size,
                              hipStream_t stream) {
    const float* x  = (const float*)d_in[0];
    const float* rw = (const float*)d_in[1];
    const float* gw = (const float*)d_in[2];
    const float* uw = (const float*)d_in[3];
    const float* dw = (const float*)d_in[4];
    float* out = (float*)d_out;
    float* logits = out + (size_t)T_TOK * HIDDEN;

    int* counts  = (int*)d_ws;
    int* offsets = counts + 8;
    int* ids     = (int*)((char*)d_ws + 64);
    float* wts   = (float*)((char*)d_ws + 64 + 8 * T_TOK * 4);
    unsigned short* h = (unsigned short*)((char*)d_ws + 262144);

    hipMemsetAsync(out, 0, (size_t)T_TOK * HIDDEN * sizeof(float), stream);
    hipMemsetAsync(counts, 0, 8 * sizeof(int), stream);

    router_kernel<<<T_TOK / 4, 256, 0, stream>>>(x, rw, logits, counts, ids, wts);
    scan_kernel<<<1, 64, 0, stream>>>(counts, offsets);
    gemm_gu<<<dim3(INTER / 128, 16, NEXP), 512, 0, stream>>>(x, gw, uw, counts, offsets, ids, h);
    gemm_down<<<dim3(HIDDEN / 128, 16, NEXP * 4), 512, 0, stream>>>(h, dw, counts, offsets, ids, wts, out);
}

// Round 3
// 366.287 us; speedup vs baseline: 1.9741x; 1.1650x over previous
//
#include <hip/hip_runtime.h>
#include <hip/hip_bf16.h>

#define HIDDEN 1024
#define INTER 4096
#define NEXP 8
#define T_TOK 2048

typedef short bf16x8 __attribute__((ext_vector_type(8)));
typedef float f32x4 __attribute__((ext_vector_type(4)));

__device__ __forceinline__ unsigned short f2bf(float f) {
    union { float f; unsigned int u; } v; v.f = f;
    unsigned int u = v.u;
    unsigned int r = (u + 0x7FFFu + ((u >> 16) & 1u)) >> 16;
    return (unsigned short)r;
}

// truncating fp32->bf16 pack of 4 floats -> 2 dwords (v_perm_b32 x2)
__device__ __forceinline__ uint2 pack4trunc(float4 v) {
    union { float4 f; unsigned short s[8]; } u; u.f = v;
    uint2 r;
    r.x = (unsigned int)u.s[1] | ((unsigned int)u.s[3] << 16);
    r.y = (unsigned int)u.s[5] | ((unsigned int)u.s[7] << 16);
    return r;
}

// raw barrier: NO vmcnt drain (global prefetch stays in flight across it).
// lgkmcnt(0) first: own ds_writes retired (visibility) / ds_reads consumed.
__device__ __forceinline__ void block_sync() {
    asm volatile("s_waitcnt lgkmcnt(0)" ::: "memory");
    __builtin_amdgcn_s_barrier();
    asm volatile("" ::: "memory");
}

// ---------------- K1: router (fp32 exact) ----------------
__global__ void router_kernel(const float* __restrict__ x,
                              const float* __restrict__ rw,
                              float* __restrict__ logits_out,
                              int* __restrict__ counts,
                              int* __restrict__ ids,
                              float* __restrict__ wts) {
    int t = blockIdx.x * 4 + (threadIdx.x >> 6);
    int lane = threadIdx.x & 63;
    if (t >= T_TOK) return;
    const float4* xr = (const float4*)(x + (size_t)t * HIDDEN);
    float acc[NEXP];
#pragma unroll
    for (int e = 0; e < NEXP; e++) acc[e] = 0.f;
#pragma unroll
    for (int c = 0; c < 4; c++) {
        float4 xv = xr[lane + c * 64];
#pragma unroll
        for (int e = 0; e < NEXP; e++) {
            float4 wv = ((const float4*)(rw + (size_t)e * HIDDEN))[lane + c * 64];
            acc[e] += xv.x * wv.x + xv.y * wv.y + xv.z * wv.z + xv.w * wv.w;
        }
    }
#pragma unroll
    for (int e = 0; e < NEXP; e++) {
        float v = acc[e];
        for (int off = 32; off >= 1; off >>= 1) v += __shfl_xor(v, off, 64);
        acc[e] = v;
    }
    if (lane == 0) {
        float* lo = logits_out + (size_t)t * NEXP;
        float mx = acc[0];
#pragma unroll
        for (int e = 1; e < NEXP; e++) mx = fmaxf(mx, acc[e]);
        float p[NEXP], s = 0.f;
#pragma unroll
        for (int e = 0; e < NEXP; e++) { p[e] = __expf(acc[e] - mx); s += p[e]; }
        float inv = 1.f / s;
#pragma unroll
        for (int e = 0; e < NEXP; e++) { p[e] *= inv; lo[e] = acc[e]; }
        int i1 = 0;
#pragma unroll
        for (int e = 1; e < NEXP; e++) if (p[e] > p[i1]) i1 = e;
        int i2 = (i1 == 0) ? 1 : 0;
#pragma unroll
        for (int e = 0; e < NEXP; e++) if (e != i1 && e != i2 && p[e] > p[i2]) i2 = e;
        int s1 = atomicAdd(&counts[i1], 1);
        ids[i1 * T_TOK + s1] = t; wts[i1 * T_TOK + s1] = p[i1];
        int s2 = atomicAdd(&counts[i2], 1);
        ids[i2 * T_TOK + s2] = t; wts[i2 * T_TOK + s2] = p[i2];
    }
}

__global__ void scan_kernel(const int* __restrict__ counts, int* __restrict__ offsets) {
    if (threadIdx.x == 0) {
        int s = 0;
        for (int e = 0; e < NEXP; e++) { offsets[e] = s; s += counts[e]; }
    }
}

// ---------------- K2: fused gate+up grouped GEMM + SwiGLU ----------------
// BM=256 tokens x BN=128 inter, BK=32, 16 waves (4x4), double-buffered LDS,
// raw-barrier pipeline (1 barrier/iter), K-major LDS (conflict-free reads).
// LDS per buffer: A 16KB | Bg 8KB | Bu 8KB = 32KB; x2 = 64KB.
__global__ __launch_bounds__(1024) void gemm_gu(
    const float* __restrict__ x, const float* __restrict__ gw, const float* __restrict__ uw,
    const int* __restrict__ counts, const int* __restrict__ offsets,
    const int* __restrict__ ids, unsigned short* __restrict__ h) {
    const int e = blockIdx.z;
    const int cnt = counts[e];
    const int mt = blockIdx.y;
    if (mt * 256 >= cnt) return;
    const int nt = blockIdx.x;                    // 32 tiles of 128 inter
    const int tid = threadIdx.x;
    const int lane = tid & 63, wid = tid >> 6;
    const int wm = wid >> 2, wn = wid & 3;        // 4 x 4 waves: 64 rows x 32 cols each

    __shared__ __align__(16) char lds[65536];

    const float* gbase = gw + (size_t)e * INTER * HIDDEN;
    const float* ubase = uw + (size_t)e * INTER * HIDDEN;

    // A staging: 256 rows x 32 K fp32; thread -> (row=idx>>3, c4=idx&7), j=0..1
    unsigned int aoff[2], wA[2];
#pragma unroll
    for (int j = 0; j < 2; j++) {
        int idx = j * 1024 + tid;
        int row = idx >> 3, c4 = idx & 7;
        int li = mt * 256 + row; if (li >= cnt) li = cnt - 1;
        int gid = ids[e * T_TOK + li];
        aoff[j] = (unsigned int)(gid * HIDDEN + c4 * 4);
        wA[j] = (unsigned int)((c4 >> 1) * 4096 + row * 16 + (c4 & 1) * 8);
    }
    // B staging: 128 rows x 32 K fp32; thread -> (row=tid>>3, c4=tid&7)
    unsigned int boff, wB;
    {
        int row = tid >> 3, c4 = tid & 7;
        boff = (unsigned int)((nt * 128 + row) * HIDDEN + c4 * 4);
        wB = (unsigned int)((c4 >> 1) * 2048 + row * 16 + (c4 & 1) * 8);
    }

    f32x4 accg[4][2], accu[4][2];
#pragma unroll
    for (int mf = 0; mf < 4; mf++)
#pragma unroll
        for (int nf = 0; nf < 2; nf++)
#pragma unroll
            for (int v = 0; v < 4; v++) { accg[mf][nf][v] = 0.f; accu[mf][nf][v] = 0.f; }

    float4 av[2], gv, uv;
    av[0] = *(const float4*)(x + aoff[0]);
    av[1] = *(const float4*)(x + aoff[1]);
    gv = *(const float4*)(gbase + boff);
    uv = *(const float4*)(ubase + boff);

    for (int kt = 0; kt < 32; kt++) {
        const unsigned int bb = (unsigned int)(kt & 1) << 15;
        // write staged tile kt (counted vmcnt waits on ~4 outstanding loads)
        *(uint2*)(lds + bb + wA[0]) = pack4trunc(av[0]);
        *(uint2*)(lds + bb + wA[1]) = pack4trunc(av[1]);
        *(uint2*)(lds + bb + 16384 + wB) = pack4trunc(gv);
        *(uint2*)(lds + bb + 24576 + wB) = pack4trunc(uv);
        // prefetch tile kt+1 (stays in flight across the raw barrier)
        if (kt < 31) {
            const int ko = (kt + 1) * 32;
            av[0] = *(const float4*)(x + aoff[0] + ko);
            av[1] = *(const float4*)(x + aoff[1] + ko);
            gv = *(const float4*)(gbase + boff + ko);
            uv = *(const float4*)(ubase + boff + ko);
        }
        block_sync();
        // compute on buf[kt&1]; K-major: frag addr = c8(lane>>4)*stride + row*16
        const unsigned int kq = (unsigned int)(lane >> 4);
        bf16x8 bg[2], bu[2];
#pragma unroll
        for (int nf = 0; nf < 2; nf++) {
            unsigned int rowb = (unsigned int)(wn * 32 + nf * 16 + (lane & 15));
            bg[nf] = *(const bf16x8*)(lds + bb + 16384 + kq * 2048 + rowb * 16);
            bu[nf] = *(const bf16x8*)(lds + bb + 24576 + kq * 2048 + rowb * 16);
        }
#pragma unroll
        for (int mf = 0; mf < 4; mf++) {
            unsigned int rowa = (unsigned int)(wm * 64 + mf * 16 + (lane & 15));
            bf16x8 a = *(const bf16x8*)(lds + bb + kq * 4096 + rowa * 16);
#pragma unroll
            for (int nf = 0; nf < 2; nf++) {
                accg[mf][nf] = __builtin_amdgcn_mfma_f32_16x16x32_bf16(a, bg[nf], accg[mf][nf], 0, 0, 0);
                accu[mf][nf] = __builtin_amdgcn_mfma_f32_16x16x32_bf16(a, bu[nf], accu[mf][nf], 0, 0, 0);
            }
        }
    }

    const int hoff = offsets[e];
#pragma unroll
    for (int mf = 0; mf < 4; mf++)
#pragma unroll
        for (int v = 0; v < 4; v++) {
            int il = wm * 64 + mf * 16 + ((lane >> 4) << 2) + v;
            int i = mt * 256 + il;
            if (i < cnt) {
                size_t rowbase = (size_t)(hoff + i) * INTER + nt * 128 + wn * 32 + (lane & 15);
#pragma unroll
                for (int nf = 0; nf < 2; nf++) {
                    float g = accg[mf][nf][v], u = accu[mf][nf][v];
                    float sg = g / (1.f + __expf(-g));
                    h[rowbase + nf * 16] = f2bf(sg * u);
                }
            }
        }
}

// ---------------- K3: down grouped GEMM + weighted scatter-add ----------------
// BM=256 rows x BN=256 hidden, BK=32, K split 4 ways, 16 waves, dbuf raw-barrier.
// LDS per buffer: A 16KB | B 16KB = 32KB; x2 = 64KB.
__global__ __launch_bounds__(1024) void gemm_down(
    const unsigned short* __restrict__ h, const float* __restrict__ dw,
    const int* __restrict__ counts, const int* __restrict__ offsets,
    const int* __restrict__ ids, const float* __restrict__ wts,
    float* __restrict__ out) {
    const int ez = blockIdx.z;                    // e*4 + ksplit
    const int e = ez >> 2, ksp = ez & 3;
    const int cnt = counts[e];
    const int mt = blockIdx.y;
    if (mt * 256 >= cnt) return;
    const int nt = blockIdx.x;                    // 4 tiles of 256 hidden
    const int tid = threadIdx.x;
    const int lane = tid & 63, wid = tid >> 6;
    const int wm = wid >> 2, wn = wid & 3;        // 4x4 waves: 64 rows x 64 cols each

    __shared__ __align__(16) char lds[65536];

    const int hoff = offsets[e];
    const float* dbase = dw + (size_t)e * HIDDEN * INTER;

    // A staging (h, bf16): 256 rows x 32 K; thread -> (row=tid>>2, c8=tid&3)
    unsigned int aoff, wAo;
    {
        int row = tid >> 2, c8 = tid & 3;
        int li = mt * 256 + row; if (li >= cnt) li = cnt - 1;
        aoff = (unsigned int)((hoff + li) * INTER + ksp * 1024 + c8 * 8);
        wAo = (unsigned int)(c8 * 4096 + row * 16);
    }
    // B staging (dw, fp32): 256 rows x 32 K; thread -> (row=idx>>3, c4=idx&7), j=0..1
    unsigned int boff[2], wB[2];
#pragma unroll
    for (int j = 0; j < 2; j++) {
        int idx = j * 1024 + tid;
        int row = idx >> 3, c4 = idx & 7;
        boff[j] = (unsigned int)((nt * 256 + row) * INTER + ksp * 1024 + c4 * 4);
        wB[j] = (unsigned int)(16384 + (c4 >> 1) * 4096 + row * 16 + (c4 & 1) * 8);
    }

    f32x4 acc[4][4];
#pragma unroll
    for (int mf = 0; mf < 4; mf++)
#pragma unroll
        for (int nf = 0; nf < 4; nf++)
#pragma unroll
            for (int v = 0; v < 4; v++) acc[mf][nf][v] = 0.f;

    int4 avv; float4 bv[2];
    avv = *(const int4*)(h + aoff);
    bv[0] = *(const float4*)(dbase + boff[0]);
    bv[1] = *(const float4*)(dbase + boff[1]);

    for (int kt = 0; kt < 32; kt++) {
        const unsigned int bb = (unsigned int)(kt & 1) << 15;
        *(int4*)(lds + bb + wAo) = avv;
        *(uint2*)(lds + bb + wB[0]) = pack4trunc(bv[0]);
        *(uint2*)(lds + bb + wB[1]) = pack4trunc(bv[1]);
        if (kt < 31) {
            const int ko = (kt + 1) * 32;
            avv = *(const int4*)(h + aoff + ko);
            bv[0] = *(const float4*)(dbase + boff[0] + ko);
            bv[1] = *(const float4*)(dbase + boff[1] + ko);
        }
        block_sync();
        const unsigned int kq = (unsigned int)(lane >> 4);
        bf16x8 bf[4];
#pragma unroll
        for (int nf = 0; nf < 4; nf++) {
            unsigned int rowb = (unsigned int)(wn * 64 + nf * 16 + (lane & 15));
            bf[nf] = *(const bf16x8*)(lds + bb + 16384 + kq * 4096 + rowb * 16);
        }
#pragma unroll
        for (int mf = 0; mf < 4; mf++) {
            unsigned int rowa = (unsigned int)(wm * 64 + mf * 16 + (lane & 15));
            bf16x8 a = *(const bf16x8*)(lds + bb + kq * 4096 + rowa * 16);
#pragma unroll
            for (int nf = 0; nf < 4; nf++)
                acc[mf][nf] = __builtin_amdgcn_mfma_f32_16x16x32_bf16(a, bf[nf], acc[mf][nf], 0, 0, 0);
        }
    }

#pragma unroll
    for (int mf = 0; mf < 4; mf++)
#pragma unroll
        for (int v = 0; v < 4; v++) {
            int il = wm * 64 + mf * 16 + ((lane >> 4) << 2) + v;
            int i = mt * 256 + il;
            if (i < cnt) {
                int t = ids[e * T_TOK + i];
                float w = wts[e * T_TOK + i];
                float* orow = out + (size_t)t * HIDDEN + nt * 256 + wn * 64 + (lane & 15);
#pragma unroll
                for (int nf = 0; nf < 4; nf++)
                    atomicAdd(orow + nf * 16, w * acc[mf][nf][v]);
            }
        }
}

extern "C" void kernel_launch(void* const* d_in, const int* in_sizes, int n_in,
                              void* d_out, int out_size, void* d_ws, size_t ws_size,
                              hipStream_t stream) {
    const float* x  = (const float*)d_in[0];
    const float* rw = (const float*)d_in[1];
    const float* gw = (const float*)d_in[2];
    const float* uw = (const float*)d_in[3];
    const float* dw = (const float*)d_in[4];
    float* out = (float*)d_out;
    float* logits = out + (size_t)T_TOK * HIDDEN;

    int* counts  = (int*)d_ws;
    int* offsets = counts + 8;
    int* ids     = (int*)((char*)d_ws + 64);
    float* wts   = (float*)((char*)d_ws + 64 + 8 * T_TOK * 4);
    unsigned short* h = (unsigned short*)((char*)d_ws + 262144);

    hipMemsetAsync(out, 0, (size_t)T_TOK * HIDDEN * sizeof(float), stream);
    hipMemsetAsync(counts, 0, 8 * sizeof(int), stream);

    router_kernel<<<T_TOK / 4, 256, 0, stream>>>(x, rw, logits, counts, ids, wts);
    scan_kernel<<<1, 64, 0, stream>>>(counts, offsets);
    gemm_gu<<<dim3(INTER / 128, 8, NEXP), 1024, 0, stream>>>(x, gw, uw, counts, offsets, ids, h);
    gemm_down<<<dim3(HIDDEN / 256, 8, NEXP * 4), 1024, 0, stream>>>(h, dw, counts, offsets, ids, wts, out);
}